// Round 13
// baseline (448.479 us; speedup 1.0000x reference)
//
#include <hip/hip_runtime.h>
#include <hip/hip_cooperative_groups.h>
#include <hip/hip_bf16.h>

namespace cg = cooperative_groups;

#define DIM 256
#define CAP 64
#define GEMM_BX 64

typedef short bf16x8 __attribute__((ext_vector_type(8)));
typedef float f32x4  __attribute__((ext_vector_type(4)));
typedef unsigned int u32x4 __attribute__((ext_vector_type(4)));

__device__ __forceinline__ unsigned short f2b(float f) {
    union { __hip_bfloat16 h; unsigned short u; } cv;
    cv.h = __float2bfloat16(f);
    return cv.u;
}
// accumulate 8 bf16 (one u32x4) into a[0..7]
__device__ __forceinline__ void acc8(u32x4 u, float* a) {
    a[0] += __uint_as_float(u.x << 16); a[1] += __uint_as_float(u.x & 0xffff0000u);
    a[2] += __uint_as_float(u.y << 16); a[3] += __uint_as_float(u.y & 0xffff0000u);
    a[4] += __uint_as_float(u.z << 16); a[5] += __uint_as_float(u.z & 0xffff0000u);
    a[6] += __uint_as_float(u.w << 16); a[7] += __uint_as_float(u.w & 0xffff0000u);
}

// ---- ws layout (bytes) ----
#define OFF_FILL   0
#define OFF_WT1    262144
#define OFF_WT2    393216
#define OFF_BUCKET 524288
#define OFF_AGG    6924544ull
#define OFF_YB     32524544ull
#define NEED_BF    (OFF_YB + 25600000ull)

// ---- shared device helpers (used by mega path AND R10 fallback path) ----
__device__ __forceinline__ void wt_one(int t, const float* __restrict__ W1,
                                       const float* __restrict__ W2,
                                       unsigned short* __restrict__ wt1,
                                       unsigned short* __restrict__ wt2) {
    int k = t & 255, nn = t >> 8;
    wt1[t] = f2b(W1[k * DIM + nn]);
    wt2[t] = f2b(W2[k * DIM + nn]);
}

// scaled slice-major yb chunk t (coalesced write; 4-lane group reads 128B line)
__device__ __forceinline__ void yb_one(int t, int n, const int* __restrict__ fill,
                                       const float* __restrict__ x,
                                       u32x4* __restrict__ yb) {
    int nN4  = n * 4;
    int s    = t / nN4;
    int rest = t - s * nN4;
    int node = rest >> 2;
    int ch   = rest & 3;
    int g    = s * 4 + ch;
    float d = rsqrtf((float)(1 + fill[node]));
    const f32x4* xp = (const f32x4*)x + ((size_t)node * 64 + g * 2);
    f32x4 v0 = xp[0], v1 = xp[1];
    u32x4 rr;
    rr.x = (unsigned)f2b(d * v0.x) | ((unsigned)f2b(d * v0.y) << 16);
    rr.y = (unsigned)f2b(d * v0.z) | ((unsigned)f2b(d * v0.w) << 16);
    rr.z = (unsigned)f2b(d * v1.x) | ((unsigned)f2b(d * v1.y) << 16);
    rr.w = (unsigned)f2b(d * v1.z) | ((unsigned)f2b(d * v1.w) << 16);
    yb[t] = rr;
}

// v9 pipelined per-node aggregation over one slice table (R10-proven: 54.7us,
// FETCH 54MB). 2-deep idx pipeline + double-buffered gather regs.
__device__ __forceinline__ void agg_one(const u32x4* __restrict__ ybs,
                                        const int* __restrict__ fill,
                                        const unsigned short* __restrict__ bucket,
                                        u32x4* __restrict__ aggbf,
                                        int n, int node, int ch, int slice) {
    int c = __builtin_nontemporal_load(&fill[node]);
    float di = rsqrtf((float)(1 + c));
    if (c > CAP) c = CAP;
    const unsigned short* bk = bucket + (size_t)node * CAP;

    float a[8];
#pragma unroll
    for (int i = 0; i < 8; i++) a[i] = 0.f;
    acc8(ybs[(size_t)node * 4 + ch], a);        // self row

#define EXTRACT8(iv, j) \
    int j##0 = iv.x & 0xffff, j##1 = iv.x >> 16, j##2 = iv.y & 0xffff, j##3 = iv.y >> 16, \
        j##4 = iv.z & 0xffff, j##5 = iv.z >> 16, j##6 = iv.w & 0xffff, j##7 = iv.w >> 16

    int full = c & ~7;
    if (full) {
        u32x4 g[8], h[8];
        u32x4 iv0 = *(const u32x4*)bk;
        {
            EXTRACT8(iv0, q);
            g[0] = ybs[q0 * 4 + ch]; g[1] = ybs[q1 * 4 + ch];
            g[2] = ybs[q2 * 4 + ch]; g[3] = ybs[q3 * 4 + ch];
            g[4] = ybs[q4 * 4 + ch]; g[5] = ybs[q5 * 4 + ch];
            g[6] = ybs[q6 * 4 + ch]; g[7] = ybs[q7 * 4 + ch];
        }
        u32x4 iv1 = *(const u32x4*)(bk + ((8 < full) ? 8 : 0));
        for (int k = 8; k < full; k += 8) {
            u32x4 ivn = *(const u32x4*)(bk + ((k + 8 < full) ? k + 8 : 0));
            {
                EXTRACT8(iv1, q);
                h[0] = ybs[q0 * 4 + ch]; h[1] = ybs[q1 * 4 + ch];
                h[2] = ybs[q2 * 4 + ch]; h[3] = ybs[q3 * 4 + ch];
                h[4] = ybs[q4 * 4 + ch]; h[5] = ybs[q5 * 4 + ch];
                h[6] = ybs[q6 * 4 + ch]; h[7] = ybs[q7 * 4 + ch];
            }
#pragma unroll
            for (int i = 0; i < 8; i++) acc8(g[i], a);
#pragma unroll
            for (int i = 0; i < 8; i++) g[i] = h[i];
            iv1 = ivn;
        }
#pragma unroll
        for (int i = 0; i < 8; i++) acc8(g[i], a);
    }

    int rem = c - full;
    if (rem) {
        u32x4 iv = *(const u32x4*)(bk + full);
        EXTRACT8(iv, q);
        q1 = (rem > 1) ? q1 : 0;
        q2 = (rem > 2) ? q2 : 0;
        q3 = (rem > 3) ? q3 : 0;
        q4 = (rem > 4) ? q4 : 0;
        q5 = (rem > 5) ? q5 : 0;
        q6 = (rem > 6) ? q6 : 0;
        u32x4 r0 = ybs[q0 * 4 + ch];
        u32x4 r1 = ybs[q1 * 4 + ch];
        u32x4 r2 = ybs[q2 * 4 + ch];
        u32x4 r3 = ybs[q3 * 4 + ch];
        u32x4 r4 = ybs[q4 * 4 + ch];
        u32x4 r5 = ybs[q5 * 4 + ch];
        u32x4 r6 = ybs[q6 * 4 + ch];
        acc8(r0, a);
        if (rem > 1) acc8(r1, a);
        if (rem > 2) acc8(r2, a);
        if (rem > 3) acc8(r3, a);
        if (rem > 4) acc8(r4, a);
        if (rem > 5) acc8(r5, a);
        if (rem > 6) acc8(r6, a);
    }
#undef EXTRACT8

    u32x4 r;
    r.x = (unsigned)f2b(a[0] * di) | ((unsigned)f2b(a[1] * di) << 16);
    r.y = (unsigned)f2b(a[2] * di) | ((unsigned)f2b(a[3] * di) << 16);
    r.z = (unsigned)f2b(a[4] * di) | ((unsigned)f2b(a[5] * di) << 16);
    r.w = (unsigned)f2b(a[6] * di) | ((unsigned)f2b(a[7] * di) << 16);
    __builtin_nontemporal_store(r, &aggbf[(size_t)node * 32 + slice * 4 + ch]);
}

// R12b cooperative mega-kernel: phases A (zero fill + wt) / B (bucket atomics)
// / C (scaled slice-major yb) / D (XCD-pinned pipelined agg) separated by
// grid.sync(). Collapses memset+fill+prep+agg (4 dispatches + ~40us gaps).
__launch_bounds__(256, 4)
__global__ void k_mega(const int* __restrict__ src, const int* __restrict__ dst,
                       int* __restrict__ fill, unsigned short* __restrict__ bucket,
                       const float* __restrict__ x, u32x4* __restrict__ yb,
                       const float* __restrict__ W1, const float* __restrict__ W2,
                       unsigned short* __restrict__ wt1, unsigned short* __restrict__ wt2,
                       u32x4* __restrict__ aggbf, int n, int E) {
    cg::grid_group grid = cg::this_grid();
    const int bid  = blockIdx.x;
    const int nblk = gridDim.x;           // multiple of 8
    const int tid  = threadIdx.x;
    const int n8   = n * 32;              // 16B chunks in yb

    // ---- Phase A: zero fill + transpose-convert W1/W2 ----
    {
        int zfB = (n + 255) >> 8;
        int totalA = zfB + 256;           // 256 blocks cover DIM*DIM = 65536
        for (int v = bid; v < totalA; v += nblk) {
            if (v < zfB) {
                int i = v * 256 + tid;
                if (i < n) fill[i] = 0;
            } else {
                wt_one((v - zfB) * 256 + tid, W1, W2, wt1, wt2);
            }
        }
    }
    grid.sync();

    // ---- Phase B: bucket fill (atomic scatter) ----
    {
        int fB = (E + 255) >> 8;
        for (int v = bid; v < fB; v += nblk) {
            int e = v * 256 + tid;
            if (e < E) {
                int d = dst[e];
                int pos = atomicAdd(&fill[d], 1);
                if (pos < CAP) bucket[d * CAP + pos] = (unsigned short)src[e];
            }
        }
    }
    grid.sync();

    // ---- Phase C: scaled slice-major yb ----
    {
        int ybB = (n8 + 255) >> 8;
        for (int v = bid; v < ybB; v += nblk) {
            int t = v * 256 + tid;
            if (t < n8) yb_one(t, n, fill, x, yb);
        }
    }
    grid.sync();

    // ---- Phase D: pipelined agg, slice fixed per block (XCD-pinned) ----
    {
        int slice = bid & 7;
        const u32x4* ybs = yb + (size_t)slice * n * 4;
        int grp = tid >> 2;
        int ch  = tid & 3;
        int nbTot = (n + 63) >> 6;
        for (int nb = bid >> 3; nb < nbTot; nb += nblk >> 3) {
            int node = nb * 64 + grp;
            if (node < n) agg_one(ybs, fill, bucket, aggbf, n, node, ch, slice);
        }
    }
}

// ---- R10 fallback path (proven 239us) ----
__global__ void k_fill(const int* __restrict__ src, const int* __restrict__ dst,
                       int* __restrict__ fill, unsigned short* __restrict__ bucket, int nE) {
    int e = blockIdx.x * blockDim.x + threadIdx.x;
    if (e < nE) {
        int d = dst[e];
        int pos = atomicAdd(&fill[d], 1);
        if (pos < CAP) bucket[d * CAP + pos] = (unsigned short)src[e];
    }
}

__global__ void k_prep(const float* __restrict__ x, const int* __restrict__ fill,
                       u32x4* __restrict__ yb,
                       const float* __restrict__ W1, const float* __restrict__ W2,
                       unsigned short* __restrict__ wt1, unsigned short* __restrict__ wt2,
                       int nybBlocks, int n8, int n) {
    if ((int)blockIdx.x < nybBlocks) {
        int t = blockIdx.x * 256 + threadIdx.x;
        if (t < n8) yb_one(t, n, fill, x, yb);
    } else {
        int t = (blockIdx.x - nybBlocks) * 256 + threadIdx.x;
        if (t < DIM * DIM) wt_one(t, W1, W2, wt1, wt2);
    }
}

__launch_bounds__(256, 4)
__global__ void k_agg_bf(const u32x4* __restrict__ yb, const int* __restrict__ fill,
                         const unsigned short* __restrict__ bucket,
                         u32x4* __restrict__ aggbf, int n) {
    int slice = blockIdx.x & 7;
    int nb    = blockIdx.x >> 3;
    int grp   = threadIdx.x >> 2;
    int ch    = threadIdx.x & 3;
    int node  = nb * 64 + grp;
    if (node >= n) return;
    const u32x4* ybs = yb + (size_t)slice * n * 4;
    agg_one(ybs, fill, bucket, aggbf, n, node, ch, slice);
}

__global__ void k_agg_f32(const float4* __restrict__ x4, const int* __restrict__ fill,
                          const unsigned short* __restrict__ bucket,
                          ushort4* __restrict__ aggbf, int n) {
    int node = (blockIdx.x * blockDim.x + threadIdx.x) >> 6;
    int lane = threadIdx.x & 63;
    if (node >= n) return;

    int c = fill[node];
    float di = rsqrtf((float)(1 + c));
    if (c > CAP) c = CAP;

    float4 xi = x4[(size_t)node * 64 + lane];
    float a0 = di * xi.x, a1 = di * xi.y, a2 = di * xi.z, a3 = di * xi.w;

    const unsigned short* bk = bucket + (size_t)node * CAP;
    for (int k = 0; k < c; k++) {
        int j = bk[k];
        float dj = rsqrtf((float)(1 + fill[j]));
        float4 xj = x4[(size_t)j * 64 + lane];
        a0 += dj * xj.x; a1 += dj * xj.y; a2 += dj * xj.z; a3 += dj * xj.w;
    }
    ushort4 r;
    r.x = f2b(a0 * di); r.y = f2b(a1 * di);
    r.z = f2b(a2 * di); r.w = f2b(a3 * di);
    aggbf[(size_t)node * 64 + lane] = r;
}

// GEMM v3: register-resident weight-stationary (R3 win; keep).
__launch_bounds__(256, 2)
__global__ void k_gemm(const short* __restrict__ aggbf,
                       const short* __restrict__ wt1, const short* __restrict__ wt2,
                       const float* __restrict__ b1, const float* __restrict__ b2,
                       float* __restrict__ out, int n, int ntiles) {
    __shared__ u32x4 bs[2048];   // [mat][nn 0..31][p 0..31] XOR-swizzled, 32 KB

    int c0  = blockIdx.y * 32;
    int tid = threadIdx.x;

#pragma unroll
    for (int i = 0; i < 8; i++) {
        int l = tid + i * 256;                 // 0..2047
        int m = l >> 10, rem = l & 1023, nn = rem >> 5, p = rem & 31;
        const short* base = (m == 0) ? wt1 : wt2;
        const u32x4* sp = (const u32x4*)(base + (size_t)(c0 + nn) * DIM) + p;
        bs[(m << 10) + (nn << 5) + (p ^ nn)] = *sp;
    }
    __syncthreads();

    int lane = tid & 63;
    int wave = tid >> 6;
    int lrow = lane & 15;
    int quad = lane >> 4;

    bf16x8 w1r[2][8], w2r[2][8];
#pragma unroll
    for (int ct = 0; ct < 2; ct++) {
        int nn = ct * 16 + lrow;
#pragma unroll
        for (int s = 0; s < 8; s++) {
            int p = (4 * s + quad) ^ nn;
            u32x4 u = bs[(nn << 5) + p];
            u32x4 v = bs[1024 + (nn << 5) + p];
            __builtin_memcpy(&w1r[ct][s], &u, 16);
            __builtin_memcpy(&w2r[ct][s], &v, 16);
        }
    }

    f32x4 bb1[2], bb2[2];
#pragma unroll
    for (int ct = 0; ct < 2; ct++) {
        bb1[ct] = *(const f32x4*)&b1[c0 + ct * 16 + quad * 4];
        bb2[ct] = *(const f32x4*)&b2[c0 + ct * 16 + quad * 4];
    }

    for (int t = blockIdx.x; t < ntiles; t += gridDim.x) {
        int row = t * 64 + wave * 16 + lrow;
        int r = (row < n) ? row : 0;
        const short* ap = aggbf + (size_t)r * DIM + quad * 8;

        bf16x8 A[8];
#pragma unroll
        for (int s = 0; s < 8; s++) A[s] = *(const bf16x8*)(ap + s * 32);

        f32x4 acc1[2], acc2[2];
#pragma unroll
        for (int ct = 0; ct < 2; ct++) {
            acc1[ct] = (f32x4){0.f, 0.f, 0.f, 0.f};
            acc2[ct] = (f32x4){0.f, 0.f, 0.f, 0.f};
        }

#pragma unroll
        for (int s = 0; s < 8; s++) {
#pragma unroll
            for (int ct = 0; ct < 2; ct++) {
                acc1[ct] = __builtin_amdgcn_mfma_f32_16x16x32_bf16(w1r[ct][s], A[s], acc1[ct], 0, 0, 0);
                acc2[ct] = __builtin_amdgcn_mfma_f32_16x16x32_bf16(w2r[ct][s], A[s], acc2[ct], 0, 0, 0);
            }
        }

        if (row < n) {
#pragma unroll
            for (int ct = 0; ct < 2; ct++) {
                f32x4 v;
#pragma unroll
                for (int i = 0; i < 4; i++)
                    v[i] = fmaxf(acc1[ct][i] + bb1[ct][i], 0.f) + acc2[ct][i] + bb2[ct][i];
                f32x4* dstp = (f32x4*)&out[(size_t)row * DIM + c0 + ct * 16 + quad * 4];
                __builtin_nontemporal_store(v, dstp);
            }
        }
    }
}

extern "C" void kernel_launch(void* const* d_in, const int* in_sizes, int n_in,
                              void* d_out, int out_size, void* d_ws, size_t ws_size,
                              hipStream_t stream) {
    const float* x  = (const float*)d_in[0];
    const int*   ei = (const int*)d_in[1];    // [2, E] row-major, int32
    const float* W1 = (const float*)d_in[2];
    const float* b1 = (const float*)d_in[3];
    const float* W2 = (const float*)d_in[4];
    const float* b2 = (const float*)d_in[5];
    float* out = (float*)d_out;

    int n = in_sizes[0] / DIM;                // 50000
    int E = in_sizes[1] / 2;                  // 800000
    const int* src = ei;
    const int* dst = ei + E;

    char* ws = (char*)d_ws;
    int*            fill   = (int*)(ws + OFF_FILL);
    unsigned short* wt1    = (unsigned short*)(ws + OFF_WT1);
    unsigned short* wt2    = (unsigned short*)(ws + OFF_WT2);
    unsigned short* bucket = (unsigned short*)(ws + OFF_BUCKET);
    char*           aggp   = ws + OFF_AGG;
    u32x4*          yb     = (u32x4*)(ws + OFF_YB);

    bool use_bf = (ws_size >= NEED_BF);      // constant across calls -> graph-safe

    if (use_bf) {
        // coopMode: 0 untested, 1 coop ok, -1 fallback. Decided once -> the
        // launch sequence is constant across calls (graph-safe).
        static int coopMode = 0;
        static int gridBlocks = 0;
        if (coopMode >= 0) {
            if (gridBlocks == 0) {
                int mb = 0;
                if (hipOccupancyMaxActiveBlocksPerMultiprocessor(&mb, k_mega, 256, 0)
                        != hipSuccess || mb < 2) mb = 2;
                if (mb > 8) mb = 8;
                gridBlocks = mb * 256;
            }
            u32x4* aggp4 = (u32x4*)aggp;
            void* args[] = {(void*)&src, (void*)&dst, (void*)&fill, (void*)&bucket,
                            (void*)&x, (void*)&yb, (void*)&W1, (void*)&W2,
                            (void*)&wt1, (void*)&wt2, (void*)&aggp4,
                            (void*)&n, (void*)&E};
            hipError_t err = hipLaunchCooperativeKernel((void*)k_mega,
                                                        dim3(gridBlocks), dim3(256),
                                                        args, 0, stream);
            coopMode = (err == hipSuccess) ? 1 : -1;
        }
        if (coopMode < 0) {
            // R10-proven 5-dispatch sequence
            (void)hipMemsetAsync(fill, 0, n * sizeof(int), stream);
            k_fill<<<(E + 255) / 256, 256, 0, stream>>>(src, dst, fill, bucket, E);
            int n8 = n * 32;
            int nybBlocks = (n8 + 255) / 256;
            k_prep<<<nybBlocks + 256, 256, 0, stream>>>(x, fill, yb, W1, W2,
                                                        wt1, wt2, nybBlocks, n8, n);
            int aggBlocks = ((n + 63) / 64) * 8;
            k_agg_bf<<<aggBlocks, 256, 0, stream>>>(yb, fill, bucket,
                                                    (u32x4*)aggp, n);
        }
    } else {
        (void)hipMemsetAsync(fill, 0, n * sizeof(int), stream);
        k_fill<<<(E + 255) / 256, 256, 0, stream>>>(src, dst, fill, bucket, E);
        int aggBlocks = (n * 64 + 255) / 256;
        k_agg_f32<<<aggBlocks, 256, 0, stream>>>((const float4*)x, fill, bucket,
                                                 (ushort4*)aggp, n);
        // weights still needed for gemm
        k_prep<<<256, 256, 0, stream>>>(x, fill, yb, W1, W2, wt1, wt2, 0, 0, n);
    }

    int ntiles = (n + 63) / 64;              // 782 row-tiles of 64
    dim3 ggrid(GEMM_BX, DIM / 32);           // 64 x 8 = 512 blocks (2/CU resident)
    k_gemm<<<ggrid, 256, 0, stream>>>((const short*)aggp, (const short*)wt1,
                                      (const short*)wt2, b1, b2, out, n, ntiles);
}

// Round 14
// 332.914 us; speedup vs baseline: 1.3471x; 1.3471x over previous
//
#include <hip/hip_runtime.h>
#include <hip/hip_bf16.h>

#define DIM 256
#define CAP 64
#define GEMM_BX 64

typedef short bf16x8 __attribute__((ext_vector_type(8)));
typedef float f32x4  __attribute__((ext_vector_type(4)));
typedef unsigned int u32x4 __attribute__((ext_vector_type(4)));

__device__ __forceinline__ unsigned short f2b(float f) {
    union { __hip_bfloat16 h; unsigned short u; } cv;
    cv.h = __float2bfloat16(f);
    return cv.u;
}
// accumulate 8 bf16 (one u32x4) into a[0..7]
__device__ __forceinline__ void acc8(u32x4 u, float* a) {
    a[0] += __uint_as_float(u.x << 16); a[1] += __uint_as_float(u.x & 0xffff0000u);
    a[2] += __uint_as_float(u.y << 16); a[3] += __uint_as_float(u.y & 0xffff0000u);
    a[4] += __uint_as_float(u.z << 16); a[5] += __uint_as_float(u.z & 0xffff0000u);
    a[6] += __uint_as_float(u.w << 16); a[7] += __uint_as_float(u.w & 0xffff0000u);
}

// ---- ws layout (bytes) ----
#define OFF_FILL   0
#define OFF_WT1    262144
#define OFF_WT2    393216
#define OFF_BUCKET 524288
#define OFF_AGG    6924544ull
#define OFF_YB     32524544ull
#define OFF_PERM   58124544ull
#define NEED_BF    (OFF_PERM + 131072ull)

__global__ void k_fill(const int* __restrict__ src, const int* __restrict__ dst,
                       int* __restrict__ fill, unsigned short* __restrict__ bucket, int nE) {
    int e = blockIdx.x * blockDim.x + threadIdx.x;
    if (e < nE) {
        int d = dst[e];
        int pos = atomicAdd(&fill[d], 1);
        if (pos < CAP) bucket[d * CAP + pos] = (unsigned short)src[e];
    }
}

// ---- shared device helpers ----
__device__ __forceinline__ void wt_one(int t, const float* __restrict__ W1,
                                       const float* __restrict__ W2,
                                       unsigned short* __restrict__ wt1,
                                       unsigned short* __restrict__ wt2) {
    int k = t & 255, nn = t >> 8;
    wt1[t] = f2b(W1[k * DIM + nn]);
    wt2[t] = f2b(W2[k * DIM + nn]);
}

// scaled slice-major yb chunk t (coalesced write; 4-lane group reads 128B line)
__device__ __forceinline__ void yb_one(int t, int n, const int* __restrict__ fill,
                                       const float* __restrict__ x,
                                       u32x4* __restrict__ yb) {
    int nN4  = n * 4;
    int s    = t / nN4;
    int rest = t - s * nN4;
    int node = rest >> 2;
    int ch   = rest & 3;
    int g    = s * 4 + ch;
    float d = rsqrtf((float)(1 + fill[node]));
    const f32x4* xp = (const f32x4*)x + ((size_t)node * 64 + g * 2);
    f32x4 v0 = xp[0], v1 = xp[1];
    u32x4 rr;
    rr.x = (unsigned)f2b(d * v0.x) | ((unsigned)f2b(d * v0.y) << 16);
    rr.y = (unsigned)f2b(d * v0.z) | ((unsigned)f2b(d * v0.w) << 16);
    rr.z = (unsigned)f2b(d * v1.x) | ((unsigned)f2b(d * v1.y) << 16);
    rr.w = (unsigned)f2b(d * v1.z) | ((unsigned)f2b(d * v1.w) << 16);
    yb[t] = rr;
}

// prep + (block 0) degree-bucket counting sort. Bucket = ceil(c/8) = agg
// iteration count (~6 live buckets) -> waves in agg get nodes with IDENTICAL
// chunk counts (kills max-of-16 loop divergence, the quantified residual).
// Per-wave privatized LDS hist/offs: pass1 and pass2 visit node i from the
// same thread (same i-stride), so per-(wave,bucket) counts match exactly ->
// perm is an exact permutation. Runs concurrent with 6500 yb/wt blocks: free.
__global__ void k_prep(const float* __restrict__ x, const int* __restrict__ fill,
                       u32x4* __restrict__ yb,
                       const float* __restrict__ W1, const float* __restrict__ W2,
                       unsigned short* __restrict__ wt1, unsigned short* __restrict__ wt2,
                       unsigned short* __restrict__ perm,
                       int permB, int nybBlocks, int n8, int n) {
    int bid = blockIdx.x;
    if (bid < permB) {
        __shared__ int hist[4][16];
        __shared__ int offs[4][16];
        int tid = threadIdx.x;
        int w = tid >> 6;
        if (tid < 64) hist[tid >> 4][tid & 15] = 0;
        __syncthreads();
        for (int i = tid; i < n; i += 256) {
            int c = fill[i];
            int b = (c + 7) >> 3; if (b > 15) b = 15;
            atomicAdd(&hist[w][b], 1);
        }
        __syncthreads();
        if (tid == 0) {
            int s = 0;
            for (int b = 0; b < 16; b++)
                for (int ww = 0; ww < 4; ww++) { offs[ww][b] = s; s += hist[ww][b]; }
        }
        __syncthreads();
        for (int i = tid; i < n; i += 256) {
            int c = fill[i];
            int b = (c + 7) >> 3; if (b > 15) b = 15;
            int p = atomicAdd(&offs[w][b], 1);
            perm[p] = (unsigned short)i;
        }
    } else if (bid < permB + nybBlocks) {
        int t = (bid - permB) * 256 + threadIdx.x;
        if (t < n8) yb_one(t, n, fill, x, yb);
    } else {
        int t = (bid - permB - nybBlocks) * 256 + threadIdx.x;
        if (t < DIM * DIM) wt_one(t, W1, W2, wt1, wt2);
    }
}

// v9 pipelined slice-pinned agg (R10-proven: 54.7us, FETCH 54MB) + perm
// indirection: wave's 16 groups now process equal-chunk-count nodes.
__launch_bounds__(256, 4)
__global__ void k_agg_bf(const u32x4* __restrict__ yb, const int* __restrict__ fill,
                         const unsigned short* __restrict__ bucket,
                         const unsigned short* __restrict__ perm,
                         u32x4* __restrict__ aggbf, int n) {
    int slice = blockIdx.x & 7;                 // XCD-pinned column-slice
    int nb    = blockIdx.x >> 3;                // node-block (64 nodes)
    int grp   = threadIdx.x >> 2;               // 0..63
    int ch    = threadIdx.x & 3;                // 16B chunk within 64B slice
    int idx   = nb * 64 + grp;
    if (idx >= n) return;
    int node  = perm[idx];                      // degree-bucketed order

    const u32x4* ybs = yb + (size_t)slice * n * 4;   // this XCD's 3.2MB table

    int c = __builtin_nontemporal_load(&fill[node]);
    float di = rsqrtf((float)(1 + c));
    if (c > CAP) c = CAP;
    const unsigned short* bk = bucket + (size_t)node * CAP;

    float a[8];
#pragma unroll
    for (int i = 0; i < 8; i++) a[i] = 0.f;
    acc8(ybs[(size_t)node * 4 + ch], a);        // self row

#define EXTRACT8(iv, j) \
    int j##0 = iv.x & 0xffff, j##1 = iv.x >> 16, j##2 = iv.y & 0xffff, j##3 = iv.y >> 16, \
        j##4 = iv.z & 0xffff, j##5 = iv.z >> 16, j##6 = iv.w & 0xffff, j##7 = iv.w >> 16

    int full = c & ~7;
    if (full) {
        u32x4 g[8], h[8];
        u32x4 iv0 = *(const u32x4*)bk;          // idx chunk 0
        {
            EXTRACT8(iv0, q);
            g[0] = ybs[q0 * 4 + ch]; g[1] = ybs[q1 * 4 + ch];
            g[2] = ybs[q2 * 4 + ch]; g[3] = ybs[q3 * 4 + ch];
            g[4] = ybs[q4 * 4 + ch]; g[5] = ybs[q5 * 4 + ch];
            g[6] = ybs[q6 * 4 + ch]; g[7] = ybs[q7 * 4 + ch];
        }
        u32x4 iv1 = *(const u32x4*)(bk + ((8 < full) ? 8 : 0));
        for (int k = 8; k < full; k += 8) {
            u32x4 ivn = *(const u32x4*)(bk + ((k + 8 < full) ? k + 8 : 0));
            {
                EXTRACT8(iv1, q);
                h[0] = ybs[q0 * 4 + ch]; h[1] = ybs[q1 * 4 + ch];
                h[2] = ybs[q2 * 4 + ch]; h[3] = ybs[q3 * 4 + ch];
                h[4] = ybs[q4 * 4 + ch]; h[5] = ybs[q5 * 4 + ch];
                h[6] = ybs[q6 * 4 + ch]; h[7] = ybs[q7 * 4 + ch];
            }
#pragma unroll
            for (int i = 0; i < 8; i++) acc8(g[i], a);
#pragma unroll
            for (int i = 0; i < 8; i++) g[i] = h[i];
            iv1 = ivn;
        }
#pragma unroll
        for (int i = 0; i < 8; i++) acc8(g[i], a);
    }

    int rem = c - full;                         // 0..7
    if (rem) {
        u32x4 iv = *(const u32x4*)(bk + full);  // within CAP alloc; garbage past rem
        EXTRACT8(iv, q);
        q1 = (rem > 1) ? q1 : 0;
        q2 = (rem > 2) ? q2 : 0;
        q3 = (rem > 3) ? q3 : 0;
        q4 = (rem > 4) ? q4 : 0;
        q5 = (rem > 5) ? q5 : 0;
        q6 = (rem > 6) ? q6 : 0;
        u32x4 r0 = ybs[q0 * 4 + ch];
        u32x4 r1 = ybs[q1 * 4 + ch];
        u32x4 r2 = ybs[q2 * 4 + ch];
        u32x4 r3 = ybs[q3 * 4 + ch];
        u32x4 r4 = ybs[q4 * 4 + ch];
        u32x4 r5 = ybs[q5 * 4 + ch];
        u32x4 r6 = ybs[q6 * 4 + ch];
        acc8(r0, a);
        if (rem > 1) acc8(r1, a);
        if (rem > 2) acc8(r2, a);
        if (rem > 3) acc8(r3, a);
        if (rem > 4) acc8(r4, a);
        if (rem > 5) acc8(r5, a);
        if (rem > 6) acc8(r6, a);
    }
#undef EXTRACT8

    u32x4 r;
    r.x = (unsigned)f2b(a[0] * di) | ((unsigned)f2b(a[1] * di) << 16);
    r.y = (unsigned)f2b(a[2] * di) | ((unsigned)f2b(a[3] * di) << 16);
    r.z = (unsigned)f2b(a[4] * di) | ((unsigned)f2b(a[5] * di) << 16);
    r.w = (unsigned)f2b(a[6] * di) | ((unsigned)f2b(a[7] * di) << 16);
    __builtin_nontemporal_store(r, &aggbf[(size_t)node * 32 + slice * 4 + ch]);
}

// fp32 fallback (only if ws too small for yb)
__global__ void k_agg_f32(const float4* __restrict__ x4, const int* __restrict__ fill,
                          const unsigned short* __restrict__ bucket,
                          ushort4* __restrict__ aggbf, int n) {
    int node = (blockIdx.x * blockDim.x + threadIdx.x) >> 6;
    int lane = threadIdx.x & 63;
    if (node >= n) return;

    int c = fill[node];
    float di = rsqrtf((float)(1 + c));
    if (c > CAP) c = CAP;

    float4 xi = x4[(size_t)node * 64 + lane];
    float a0 = di * xi.x, a1 = di * xi.y, a2 = di * xi.z, a3 = di * xi.w;

    const unsigned short* bk = bucket + (size_t)node * CAP;
    for (int k = 0; k < c; k++) {
        int j = bk[k];
        float dj = rsqrtf((float)(1 + fill[j]));
        float4 xj = x4[(size_t)j * 64 + lane];
        a0 += dj * xj.x; a1 += dj * xj.y; a2 += dj * xj.z; a3 += dj * xj.w;
    }
    ushort4 r;
    r.x = f2b(a0 * di); r.y = f2b(a1 * di);
    r.z = f2b(a2 * di); r.w = f2b(a3 * di);
    aggbf[(size_t)node * 64 + lane] = r;
}

// GEMM v3: register-resident weight-stationary (R3 win; keep).
__launch_bounds__(256, 2)
__global__ void k_gemm(const short* __restrict__ aggbf,
                       const short* __restrict__ wt1, const short* __restrict__ wt2,
                       const float* __restrict__ b1, const float* __restrict__ b2,
                       float* __restrict__ out, int n, int ntiles) {
    __shared__ u32x4 bs[2048];   // [mat][nn 0..31][p 0..31] XOR-swizzled, 32 KB

    int c0  = blockIdx.y * 32;
    int tid = threadIdx.x;

#pragma unroll
    for (int i = 0; i < 8; i++) {
        int l = tid + i * 256;                 // 0..2047
        int m = l >> 10, rem = l & 1023, nn = rem >> 5, p = rem & 31;
        const short* base = (m == 0) ? wt1 : wt2;
        const u32x4* sp = (const u32x4*)(base + (size_t)(c0 + nn) * DIM) + p;
        bs[(m << 10) + (nn << 5) + (p ^ nn)] = *sp;
    }
    __syncthreads();

    int lane = tid & 63;
    int wave = tid >> 6;
    int lrow = lane & 15;
    int quad = lane >> 4;

    bf16x8 w1r[2][8], w2r[2][8];
#pragma unroll
    for (int ct = 0; ct < 2; ct++) {
        int nn = ct * 16 + lrow;
#pragma unroll
        for (int s = 0; s < 8; s++) {
            int p = (4 * s + quad) ^ nn;
            u32x4 u = bs[(nn << 5) + p];
            u32x4 v = bs[1024 + (nn << 5) + p];
            __builtin_memcpy(&w1r[ct][s], &u, 16);
            __builtin_memcpy(&w2r[ct][s], &v, 16);
        }
    }

    f32x4 bb1[2], bb2[2];
#pragma unroll
    for (int ct = 0; ct < 2; ct++) {
        bb1[ct] = *(const f32x4*)&b1[c0 + ct * 16 + quad * 4];
        bb2[ct] = *(const f32x4*)&b2[c0 + ct * 16 + quad * 4];
    }

    for (int t = blockIdx.x; t < ntiles; t += gridDim.x) {
        int row = t * 64 + wave * 16 + lrow;
        int r = (row < n) ? row : 0;
        const short* ap = aggbf + (size_t)r * DIM + quad * 8;

        bf16x8 A[8];
#pragma unroll
        for (int s = 0; s < 8; s++) A[s] = *(const bf16x8*)(ap + s * 32);

        f32x4 acc1[2], acc2[2];
#pragma unroll
        for (int ct = 0; ct < 2; ct++) {
            acc1[ct] = (f32x4){0.f, 0.f, 0.f, 0.f};
            acc2[ct] = (f32x4){0.f, 0.f, 0.f, 0.f};
        }

#pragma unroll
        for (int s = 0; s < 8; s++) {
#pragma unroll
            for (int ct = 0; ct < 2; ct++) {
                acc1[ct] = __builtin_amdgcn_mfma_f32_16x16x32_bf16(w1r[ct][s], A[s], acc1[ct], 0, 0, 0);
                acc2[ct] = __builtin_amdgcn_mfma_f32_16x16x32_bf16(w2r[ct][s], A[s], acc2[ct], 0, 0, 0);
            }
        }

        if (row < n) {
#pragma unroll
            for (int ct = 0; ct < 2; ct++) {
                f32x4 v;
#pragma unroll
                for (int i = 0; i < 4; i++)
                    v[i] = fmaxf(acc1[ct][i] + bb1[ct][i], 0.f) + acc2[ct][i] + bb2[ct][i];
                f32x4* dstp = (f32x4*)&out[(size_t)row * DIM + c0 + ct * 16 + quad * 4];
                __builtin_nontemporal_store(v, dstp);
            }
        }
    }
}

extern "C" void kernel_launch(void* const* d_in, const int* in_sizes, int n_in,
                              void* d_out, int out_size, void* d_ws, size_t ws_size,
                              hipStream_t stream) {
    const float* x  = (const float*)d_in[0];
    const int*   ei = (const int*)d_in[1];    // [2, E] row-major, int32
    const float* W1 = (const float*)d_in[2];
    const float* b1 = (const float*)d_in[3];
    const float* W2 = (const float*)d_in[4];
    const float* b2 = (const float*)d_in[5];
    float* out = (float*)d_out;

    int n = in_sizes[0] / DIM;                // 50000
    int E = in_sizes[1] / 2;                  // 800000
    const int* src = ei;
    const int* dst = ei + E;

    char* ws = (char*)d_ws;
    int*            fill   = (int*)(ws + OFF_FILL);
    unsigned short* wt1    = (unsigned short*)(ws + OFF_WT1);
    unsigned short* wt2    = (unsigned short*)(ws + OFF_WT2);
    unsigned short* bucket = (unsigned short*)(ws + OFF_BUCKET);
    char*           aggp   = ws + OFF_AGG;
    u32x4*          yb     = (u32x4*)(ws + OFF_YB);
    unsigned short* perm   = (unsigned short*)(ws + OFF_PERM);

    (void)hipMemsetAsync(fill, 0, n * sizeof(int), stream);

    k_fill<<<(E + 255) / 256, 256, 0, stream>>>(src, dst, fill, bucket, E);

    bool use_bf = (ws_size >= NEED_BF);      // constant across calls -> graph-safe
    if (use_bf) {
        int n8 = n * 32;                     // 1.6M 16B chunks
        int nybBlocks = (n8 + 255) / 256;    // 6250
        // block 0: degree-bucket perm; blocks [1, nyb]: yb; tail: weights
        k_prep<<<1 + nybBlocks + 256, 256, 0, stream>>>(x, fill, yb, W1, W2,
                                                        wt1, wt2, perm,
                                                        1, nybBlocks, n8, n);
        int aggBlocks = ((n + 63) / 64) * 8; // 782*8 = 6256
        k_agg_bf<<<aggBlocks, 256, 0, stream>>>(yb, fill, bucket, perm,
                                                (u32x4*)aggp, n);
    } else {
        k_prep<<<256, 256, 0, stream>>>(x, fill, yb, W1, W2, wt1, wt2, perm,
                                        0, 0, 0, n);
        int aggBlocks = (n * 64 + 255) / 256;
        k_agg_f32<<<aggBlocks, 256, 0, stream>>>((const float4*)x, fill, bucket,
                                                 (ushort4*)aggp, n);
    }

    int ntiles = (n + 63) / 64;              // 782 row-tiles of 64
    dim3 ggrid(GEMM_BX, DIM / 32);           // 64 x 8 = 512 blocks (2/CU resident)
    k_gemm<<<ggrid, 256, 0, stream>>>((const short*)aggp, (const short*)wt1,
                                      (const short*)wt2, b1, b2, out, n, ntiles);
}

// Round 15
// 240.955 us; speedup vs baseline: 1.8613x; 1.3816x over previous
//
#include <hip/hip_runtime.h>
#include <hip/hip_bf16.h>

#define DIM 256
#define CAP 64
#define GEMM_BX 64

typedef short bf16x8 __attribute__((ext_vector_type(8)));
typedef float f32x4  __attribute__((ext_vector_type(4)));
typedef unsigned int u32x4 __attribute__((ext_vector_type(4)));

__device__ __forceinline__ unsigned short f2b(float f) {
    union { __hip_bfloat16 h; unsigned short u; } cv;
    cv.h = __float2bfloat16(f);
    return cv.u;
}
// accumulate 8 bf16 (one u32x4) into a[0..7]
__device__ __forceinline__ void acc8(u32x4 u, float* a) {
    a[0] += __uint_as_float(u.x << 16); a[1] += __uint_as_float(u.x & 0xffff0000u);
    a[2] += __uint_as_float(u.y << 16); a[3] += __uint_as_float(u.y & 0xffff0000u);
    a[4] += __uint_as_float(u.z << 16); a[5] += __uint_as_float(u.z & 0xffff0000u);
    a[6] += __uint_as_float(u.w << 16); a[7] += __uint_as_float(u.w & 0xffff0000u);
}

// ---- ws layout (bytes) ----
#define OFF_FILL   0
#define OFF_WT1    262144
#define OFF_WT2    393216
#define OFF_BUCKET 524288
#define OFF_AGG    6924544ull
#define OFF_YB     32524544ull
#define NEED_BF    (OFF_YB + 25600000ull)

// ---- shared device helpers ----
__device__ __forceinline__ void wt_one(int t, const float* __restrict__ W1,
                                       const float* __restrict__ W2,
                                       unsigned short* __restrict__ wt1,
                                       unsigned short* __restrict__ wt2) {
    int k = t & 255, nn = t >> 8;
    wt1[t] = f2b(W1[k * DIM + nn]);
    wt2[t] = f2b(W2[k * DIM + nn]);
}

// scaled slice-major yb chunk t (coalesced write; 4-lane group reads 128B line;
// single rounding: f32 x times f32 d, one f2b)
__device__ __forceinline__ void yb_one(int t, int n, const int* __restrict__ fill,
                                       const float* __restrict__ x,
                                       u32x4* __restrict__ yb) {
    int nN4  = n * 4;
    int s    = t / nN4;
    int rest = t - s * nN4;
    int node = rest >> 2;
    int ch   = rest & 3;
    int g    = s * 4 + ch;
    float d = rsqrtf((float)(1 + fill[node]));
    const f32x4* xp = (const f32x4*)x + ((size_t)node * 64 + g * 2);
    f32x4 v0 = xp[0], v1 = xp[1];
    u32x4 rr;
    rr.x = (unsigned)f2b(d * v0.x) | ((unsigned)f2b(d * v0.y) << 16);
    rr.y = (unsigned)f2b(d * v0.z) | ((unsigned)f2b(d * v0.w) << 16);
    rr.z = (unsigned)f2b(d * v1.x) | ((unsigned)f2b(d * v1.y) << 16);
    rr.w = (unsigned)f2b(d * v1.z) | ((unsigned)f2b(d * v1.w) << 16);
    yb[t] = rr;
}

// R15: fill + weight-transpose fused (wt has no dependency on fill; its 256
// blocks ride free under fill's atomic-latency idle — R11 showed fill absorbs
// co-resident streaming work). fill part: latency-bound atomic scatter.
__global__ void k_fillwt(const int* __restrict__ src, const int* __restrict__ dst,
                         int* __restrict__ fill, unsigned short* __restrict__ bucket,
                         const float* __restrict__ W1, const float* __restrict__ W2,
                         unsigned short* __restrict__ wt1, unsigned short* __restrict__ wt2,
                         int nFB, int nE) {
    int bid = blockIdx.x;
    if (bid < nFB) {
        int e = bid * 256 + threadIdx.x;
        if (e < nE) {
            int d = dst[e];
            int pos = atomicAdd(&fill[d], 1);
            if (pos < CAP) bucket[d * CAP + pos] = (unsigned short)src[e];
        }
    } else {
        int t = (bid - nFB) * 256 + threadIdx.x;
        if (t < DIM * DIM) wt_one(t, W1, W2, wt1, wt2);
    }
}

// R15: yb build, slice-pinned (bid&7 = slice = agg's XCD): the dirty yb lines
// land in the SAME XCD's private L2 that agg will gather from -> part of agg's
// 25.6MB first-touch becomes warm L2 hits. Same index math as R10 (single
// rounding), same coalescing.
__global__ void k_prep_yb(const float* __restrict__ x, const int* __restrict__ fill,
                          u32x4* __restrict__ yb, int n) {
    int nN4 = n * 4;
    int v = (blockIdx.x >> 3) * 256 + threadIdx.x;   // chunk within slice
    if (v < nN4) yb_one((blockIdx.x & 7) * nN4 + v, n, fill, x, yb);
}

// v9 pipelined slice-pinned agg (R10-proven: 54.7us, FETCH 54MB).
// 2-deep idx pipeline + double-buffered gather regs. (perm experiment R14
// reverted: single-block sort serialized at ~100us.)
__launch_bounds__(256, 4)
__global__ void k_agg_bf(const u32x4* __restrict__ yb, const int* __restrict__ fill,
                         const unsigned short* __restrict__ bucket,
                         u32x4* __restrict__ aggbf, int n) {
    int slice = blockIdx.x & 7;                 // XCD-pinned column-slice
    int nb    = blockIdx.x >> 3;                // node-block (64 nodes)
    int grp   = threadIdx.x >> 2;               // 0..63: node within block
    int ch    = threadIdx.x & 3;                // 16B chunk within 64B slice
    int node  = nb * 64 + grp;
    if (node >= n) return;

    const u32x4* ybs = yb + (size_t)slice * n * 4;   // this XCD's 3.2MB table

    int c = __builtin_nontemporal_load(&fill[node]);
    float di = rsqrtf((float)(1 + c));
    if (c > CAP) c = CAP;
    const unsigned short* bk = bucket + (size_t)node * CAP;

    float a[8];
#pragma unroll
    for (int i = 0; i < 8; i++) a[i] = 0.f;
    acc8(ybs[(size_t)node * 4 + ch], a);        // self row

#define EXTRACT8(iv, j) \
    int j##0 = iv.x & 0xffff, j##1 = iv.x >> 16, j##2 = iv.y & 0xffff, j##3 = iv.y >> 16, \
        j##4 = iv.z & 0xffff, j##5 = iv.z >> 16, j##6 = iv.w & 0xffff, j##7 = iv.w >> 16

    int full = c & ~7;
    if (full) {
        u32x4 g[8], h[8];
        u32x4 iv0 = *(const u32x4*)bk;          // idx chunk 0
        {
            EXTRACT8(iv0, q);
            g[0] = ybs[q0 * 4 + ch]; g[1] = ybs[q1 * 4 + ch];
            g[2] = ybs[q2 * 4 + ch]; g[3] = ybs[q3 * 4 + ch];
            g[4] = ybs[q4 * 4 + ch]; g[5] = ybs[q5 * 4 + ch];
            g[6] = ybs[q6 * 4 + ch]; g[7] = ybs[q7 * 4 + ch];
        }
        u32x4 iv1 = *(const u32x4*)(bk + ((8 < full) ? 8 : 0));
        for (int k = 8; k < full; k += 8) {
            u32x4 ivn = *(const u32x4*)(bk + ((k + 8 < full) ? k + 8 : 0));
            {
                EXTRACT8(iv1, q);
                h[0] = ybs[q0 * 4 + ch]; h[1] = ybs[q1 * 4 + ch];
                h[2] = ybs[q2 * 4 + ch]; h[3] = ybs[q3 * 4 + ch];
                h[4] = ybs[q4 * 4 + ch]; h[5] = ybs[q5 * 4 + ch];
                h[6] = ybs[q6 * 4 + ch]; h[7] = ybs[q7 * 4 + ch];
            }
#pragma unroll
            for (int i = 0; i < 8; i++) acc8(g[i], a);
#pragma unroll
            for (int i = 0; i < 8; i++) g[i] = h[i];
            iv1 = ivn;
        }
#pragma unroll
        for (int i = 0; i < 8; i++) acc8(g[i], a);
    }

    int rem = c - full;                         // 0..7
    if (rem) {
        u32x4 iv = *(const u32x4*)(bk + full);  // within CAP alloc; garbage past rem
        EXTRACT8(iv, q);
        q1 = (rem > 1) ? q1 : 0;
        q2 = (rem > 2) ? q2 : 0;
        q3 = (rem > 3) ? q3 : 0;
        q4 = (rem > 4) ? q4 : 0;
        q5 = (rem > 5) ? q5 : 0;
        q6 = (rem > 6) ? q6 : 0;
        u32x4 r0 = ybs[q0 * 4 + ch];
        u32x4 r1 = ybs[q1 * 4 + ch];
        u32x4 r2 = ybs[q2 * 4 + ch];
        u32x4 r3 = ybs[q3 * 4 + ch];
        u32x4 r4 = ybs[q4 * 4 + ch];
        u32x4 r5 = ybs[q5 * 4 + ch];
        u32x4 r6 = ybs[q6 * 4 + ch];
        acc8(r0, a);
        if (rem > 1) acc8(r1, a);
        if (rem > 2) acc8(r2, a);
        if (rem > 3) acc8(r3, a);
        if (rem > 4) acc8(r4, a);
        if (rem > 5) acc8(r5, a);
        if (rem > 6) acc8(r6, a);
    }
#undef EXTRACT8

    u32x4 r;
    r.x = (unsigned)f2b(a[0] * di) | ((unsigned)f2b(a[1] * di) << 16);
    r.y = (unsigned)f2b(a[2] * di) | ((unsigned)f2b(a[3] * di) << 16);
    r.z = (unsigned)f2b(a[4] * di) | ((unsigned)f2b(a[5] * di) << 16);
    r.w = (unsigned)f2b(a[6] * di) | ((unsigned)f2b(a[7] * di) << 16);
    __builtin_nontemporal_store(r, &aggbf[(size_t)node * 32 + slice * 4 + ch]);
}

// fp32 fallback (only if ws too small for yb)
__global__ void k_agg_f32(const float4* __restrict__ x4, const int* __restrict__ fill,
                          const unsigned short* __restrict__ bucket,
                          ushort4* __restrict__ aggbf, int n) {
    int node = (blockIdx.x * blockDim.x + threadIdx.x) >> 6;
    int lane = threadIdx.x & 63;
    if (node >= n) return;

    int c = fill[node];
    float di = rsqrtf((float)(1 + c));
    if (c > CAP) c = CAP;

    float4 xi = x4[(size_t)node * 64 + lane];
    float a0 = di * xi.x, a1 = di * xi.y, a2 = di * xi.z, a3 = di * xi.w;

    const unsigned short* bk = bucket + (size_t)node * CAP;
    for (int k = 0; k < c; k++) {
        int j = bk[k];
        float dj = rsqrtf((float)(1 + fill[j]));
        float4 xj = x4[(size_t)j * 64 + lane];
        a0 += dj * xj.x; a1 += dj * xj.y; a2 += dj * xj.z; a3 += dj * xj.w;
    }
    ushort4 r;
    r.x = f2b(a0 * di); r.y = f2b(a1 * di);
    r.z = f2b(a2 * di); r.w = f2b(a3 * di);
    aggbf[(size_t)node * 64 + lane] = r;
}

// GEMM v3: register-resident weight-stationary (R3 win; keep).
__launch_bounds__(256, 2)
__global__ void k_gemm(const short* __restrict__ aggbf,
                       const short* __restrict__ wt1, const short* __restrict__ wt2,
                       const float* __restrict__ b1, const float* __restrict__ b2,
                       float* __restrict__ out, int n, int ntiles) {
    __shared__ u32x4 bs[2048];   // [mat][nn 0..31][p 0..31] XOR-swizzled, 32 KB

    int c0  = blockIdx.y * 32;
    int tid = threadIdx.x;

#pragma unroll
    for (int i = 0; i < 8; i++) {
        int l = tid + i * 256;                 // 0..2047
        int m = l >> 10, rem = l & 1023, nn = rem >> 5, p = rem & 31;
        const short* base = (m == 0) ? wt1 : wt2;
        const u32x4* sp = (const u32x4*)(base + (size_t)(c0 + nn) * DIM) + p;
        bs[(m << 10) + (nn << 5) + (p ^ nn)] = *sp;
    }
    __syncthreads();

    int lane = tid & 63;
    int wave = tid >> 6;
    int lrow = lane & 15;
    int quad = lane >> 4;

    bf16x8 w1r[2][8], w2r[2][8];
#pragma unroll
    for (int ct = 0; ct < 2; ct++) {
        int nn = ct * 16 + lrow;
#pragma unroll
        for (int s = 0; s < 8; s++) {
            int p = (4 * s + quad) ^ nn;
            u32x4 u = bs[(nn << 5) + p];
            u32x4 v = bs[1024 + (nn << 5) + p];
            __builtin_memcpy(&w1r[ct][s], &u, 16);
            __builtin_memcpy(&w2r[ct][s], &v, 16);
        }
    }

    f32x4 bb1[2], bb2[2];
#pragma unroll
    for (int ct = 0; ct < 2; ct++) {
        bb1[ct] = *(const f32x4*)&b1[c0 + ct * 16 + quad * 4];
        bb2[ct] = *(const f32x4*)&b2[c0 + ct * 16 + quad * 4];
    }

    for (int t = blockIdx.x; t < ntiles; t += gridDim.x) {
        int row = t * 64 + wave * 16 + lrow;
        int r = (row < n) ? row : 0;
        const short* ap = aggbf + (size_t)r * DIM + quad * 8;

        bf16x8 A[8];
#pragma unroll
        for (int s = 0; s < 8; s++) A[s] = *(const bf16x8*)(ap + s * 32);

        f32x4 acc1[2], acc2[2];
#pragma unroll
        for (int ct = 0; ct < 2; ct++) {
            acc1[ct] = (f32x4){0.f, 0.f, 0.f, 0.f};
            acc2[ct] = (f32x4){0.f, 0.f, 0.f, 0.f};
        }

#pragma unroll
        for (int s = 0; s < 8; s++) {
#pragma unroll
            for (int ct = 0; ct < 2; ct++) {
                acc1[ct] = __builtin_amdgcn_mfma_f32_16x16x32_bf16(w1r[ct][s], A[s], acc1[ct], 0, 0, 0);
                acc2[ct] = __builtin_amdgcn_mfma_f32_16x16x32_bf16(w2r[ct][s], A[s], acc2[ct], 0, 0, 0);
            }
        }

        if (row < n) {
#pragma unroll
            for (int ct = 0; ct < 2; ct++) {
                f32x4 v;
#pragma unroll
                for (int i = 0; i < 4; i++)
                    v[i] = fmaxf(acc1[ct][i] + bb1[ct][i], 0.f) + acc2[ct][i] + bb2[ct][i];
                f32x4* dstp = (f32x4*)&out[(size_t)row * DIM + c0 + ct * 16 + quad * 4];
                __builtin_nontemporal_store(v, dstp);
            }
        }
    }
}

extern "C" void kernel_launch(void* const* d_in, const int* in_sizes, int n_in,
                              void* d_out, int out_size, void* d_ws, size_t ws_size,
                              hipStream_t stream) {
    const float* x  = (const float*)d_in[0];
    const int*   ei = (const int*)d_in[1];    // [2, E] row-major, int32
    const float* W1 = (const float*)d_in[2];
    const float* b1 = (const float*)d_in[3];
    const float* W2 = (const float*)d_in[4];
    const float* b2 = (const float*)d_in[5];
    float* out = (float*)d_out;

    int n = in_sizes[0] / DIM;                // 50000
    int E = in_sizes[1] / 2;                  // 800000
    const int* src = ei;
    const int* dst = ei + E;

    char* ws = (char*)d_ws;
    int*            fill   = (int*)(ws + OFF_FILL);
    unsigned short* wt1    = (unsigned short*)(ws + OFF_WT1);
    unsigned short* wt2    = (unsigned short*)(ws + OFF_WT2);
    unsigned short* bucket = (unsigned short*)(ws + OFF_BUCKET);
    char*           aggp   = ws + OFF_AGG;
    u32x4*          yb     = (u32x4*)(ws + OFF_YB);

    (void)hipMemsetAsync(fill, 0, n * sizeof(int), stream);

    int nFB = (E + 255) / 256;                // 3125 fill blocks
    // fill + weight transpose fused (wt rides under fill's atomic stalls)
    k_fillwt<<<nFB + 256, 256, 0, stream>>>(src, dst, fill, bucket,
                                            W1, W2, wt1, wt2, nFB, E);

    bool use_bf = (ws_size >= NEED_BF);      // constant across calls -> graph-safe
    if (use_bf) {
        int nN4 = n * 4;                     // chunks per slice table
        int ybB = ((nN4 + 255) / 256) * 8;   // 782*8: bid&7=slice (XCD-pinned)
        k_prep_yb<<<ybB, 256, 0, stream>>>(x, fill, yb, n);
        int aggBlocks = ((n + 63) / 64) * 8; // 782*8 = 6256
        k_agg_bf<<<aggBlocks, 256, 0, stream>>>(yb, fill, bucket,
                                                (u32x4*)aggp, n);
    } else {
        int aggBlocks = (n * 64 + 255) / 256;
        k_agg_f32<<<aggBlocks, 256, 0, stream>>>((const float4*)x, fill, bucket,
                                                 (ushort4*)aggp, n);
    }

    int ntiles = (n + 63) / 64;              // 782 row-tiles of 64
    dim3 ggrid(GEMM_BX, DIM / 32);           // 64 x 8 = 512 blocks (2/CU resident)
    k_gemm<<<ggrid, 256, 0, stream>>>((const short*)aggp, (const short*)wt1,
                                      (const short*)wt2, b1, b2, out, n, ntiles);
}